// Round 2
// baseline (340.364 us; speedup 1.0000x reference)
//
#include <hip/hip_runtime.h>
#include <stdint.h>

// topk(values+indices), x: (2,4096,50257) fp32, k=50, last axis, largest, sorted.
// d_out layout (flat float32): [rows*k values][rows*k indices-as-float]
//
// Two-phase: (1) streaming threshold scan -> candidate dump into d_ws
// (bisection retry for arbitrary distributions; single pass for N(0,1));
// (2) per-row bitonic sort of <=512 candidates by (value desc, index asc)
// -- lowest-index tie-break matches jax.lax.top_k. Splitting keeps the
// scan a pure BW-bound stream (no sort bubbles at block tails).
// Fallback: monolithic single-kernel version if ws_size is too small.

#define TPB 256
#define SCAP 512   // scan/sort candidate capacity (power of two)
#define MCAP 2048  // monolithic-fallback capacity

__device__ __forceinline__ unsigned ordf(float f) {
  unsigned s = __float_as_uint(f);
  return (s & 0x80000000u) ? ~s : (s | 0x80000000u);
}
__device__ __forceinline__ float unordf(unsigned u) {
  unsigned s = (u & 0x80000000u) ? (u ^ 0x80000000u) : ~u;
  return __uint_as_float(s);
}

// Bitonic sort over np2 elements (power of two), descending by value,
// ascending index on ties. Barrier-synced across the block.
__device__ __forceinline__ void bitonic_desc(float* cv, unsigned* ci, int np2, int tid) {
  for (int sz = 2; sz <= np2; sz <<= 1) {
    for (int st = sz >> 1; st > 0; st >>= 1) {
      for (int t = tid; t < (np2 >> 1); t += TPB) {
        int i = ((t & ~(st - 1)) << 1) | (t & (st - 1));
        int j = i | st;
        bool segDesc = ((i & sz) == 0);
        float va = cv[i], vb = cv[j];
        unsigned ia = ci[i], ib = ci[j];
        bool aFirst = (va > vb) || (va == vb && ia < ib);
        if (segDesc ? !aFirst : aFirst) {
          cv[i] = vb; cv[j] = va; ci[i] = ib; ci[j] = ia;
        }
      }
      __syncthreads();
    }
  }
}

// ---------------- Phase 1: streaming scan ----------------
__global__ __launch_bounds__(TPB) void topk_scan_kernel(
    const float* __restrict__ x, float* __restrict__ wsv,
    unsigned* __restrict__ wsi, int* __restrict__ wscnt,
    int rows, int V, int k, int cap) {
  const int row = blockIdx.x;
  const int tid = threadIdx.x;
  const float* rp = x + (size_t)row * (size_t)V;

  __shared__ float cv[SCAP];
  __shared__ unsigned ci[SCAP];
  __shared__ int s_cnt;

  // Per-row 16B alignment (V odd -> row bases cycle mod 16).
  unsigned mis = (unsigned)((size_t)rp & 15u);
  int head = (int)(((16u - mis) & 15u) >> 2);
  if (head > V) head = V;
  int nvec = (V - head) >> 2;
  int tail_start = head + nvec * 4;
  const float4* vp = (const float4*)(rp + head);

  unsigned lo = 0u, hi = 0xFFFFFFFFu;
  unsigned tu = ordf(2.75f);  // ~150 expected hits/row for N(0,1), 8-sigma safe both ways
  int cnt = 0;

  for (int attempt = 0; attempt < 48; ++attempt) {
    if (tid == 0) s_cnt = 0;
    __syncthreads();
    float thr = unordf(tu);

    for (int i = tid; i < head; i += TPB) {
      float v = rp[i];
      if (v > thr) { int p = atomicAdd(&s_cnt, 1); if (p < cap) { cv[p] = v; ci[p] = (unsigned)i; } }
    }
    for (int i = tail_start + tid; i < V; i += TPB) {
      float v = rp[i];
      if (v > thr) { int p = atomicAdd(&s_cnt, 1); if (p < cap) { cv[p] = v; ci[p] = (unsigned)i; } }
    }
    for (int j = tid; j < nvec; j += TPB) {
      float4 v = vp[j];
      // Fast path: one compare per group; slow path ~1.2% of groups.
      float m = fmaxf(fmaxf(v.x, v.y), fmaxf(v.z, v.w));
      if (m > thr) {
        int base = head + 4 * j;
        if (v.x > thr) { int p = atomicAdd(&s_cnt, 1); if (p < cap) { cv[p] = v.x; ci[p] = (unsigned)(base + 0); } }
        if (v.y > thr) { int p = atomicAdd(&s_cnt, 1); if (p < cap) { cv[p] = v.y; ci[p] = (unsigned)(base + 1); } }
        if (v.z > thr) { int p = atomicAdd(&s_cnt, 1); if (p < cap) { cv[p] = v.z; ci[p] = (unsigned)(base + 2); } }
        if (v.w > thr) { int p = atomicAdd(&s_cnt, 1); if (p < cap) { cv[p] = v.w; ci[p] = (unsigned)(base + 3); } }
      }
    }
    __syncthreads();
    cnt = s_cnt;
    if (cnt >= k && cnt <= cap) break;
    if (hi <= lo + 1u) break;  // pathological ties: accept
    if (cnt > cap) lo = tu; else hi = tu;
    unsigned mid = (unsigned)(((unsigned long long)lo + (unsigned long long)hi) >> 1);
    if (mid == tu) break;
    tu = mid;
    __syncthreads();
  }
  if (cnt > cap) cnt = cap;

  if (tid == 0) wscnt[row] = cnt;
  for (int t = tid; t < cnt; t += TPB) {
    wsv[(size_t)row * cap + t] = cv[t];
    wsi[(size_t)row * cap + t] = ci[t];
  }
}

// ---------------- Phase 2: per-row sort of candidates ----------------
__global__ __launch_bounds__(TPB) void topk_sort_kernel(
    const float* __restrict__ wsv, const unsigned* __restrict__ wsi,
    const int* __restrict__ wscnt, float* __restrict__ out,
    int rows, int k, int cap, int out_half) {
  const int row = blockIdx.x;
  const int tid = threadIdx.x;

  __shared__ float cv[SCAP];
  __shared__ unsigned ci[SCAP];

  int cnt = wscnt[row];
  if (cnt > cap) cnt = cap;

  int np2 = 64;
  while (np2 < cnt) np2 <<= 1;

  for (int t = tid; t < cnt; t += TPB) {
    cv[t] = wsv[(size_t)row * cap + t];
    ci[t] = wsi[(size_t)row * cap + t];
  }
  for (int t = cnt + tid; t < np2; t += TPB) { cv[t] = -INFINITY; ci[t] = 0xFFFFFFFFu; }
  __syncthreads();

  bitonic_desc(cv, ci, np2, tid);

  float* out_vals = out;
  float* out_idx  = out + out_half;
  for (int t = tid; t < k; t += TPB) {
    out_vals[(size_t)row * k + t] = cv[t];
    out_idx[(size_t)row * k + t]  = (float)ci[t];
  }
}

// ---------------- Fallback: monolithic (proven R1 kernel) ----------------
__global__ __launch_bounds__(TPB) void topk_mono_kernel(
    const float* __restrict__ x, float* __restrict__ out,
    int rows, int V, int k, int out_half) {
  const int row = blockIdx.x;
  const int tid = threadIdx.x;
  const float* rp = x + (size_t)row * (size_t)V;

  __shared__ float cv[MCAP];
  __shared__ unsigned ci[MCAP];
  __shared__ int s_cnt;

  unsigned mis = (unsigned)((size_t)rp & 15u);
  int head = (int)(((16u - mis) & 15u) >> 2);
  if (head > V) head = V;
  int nvec = (V - head) >> 2;
  int tail_start = head + nvec * 4;
  const float4* vp = (const float4*)(rp + head);

  unsigned lo = 0u, hi = 0xFFFFFFFFu;
  unsigned tu = ordf(2.5f);
  int cnt = 0;

  for (int attempt = 0; attempt < 48; ++attempt) {
    if (tid == 0) s_cnt = 0;
    __syncthreads();
    float thr = unordf(tu);
    for (int i = tid; i < head; i += TPB) {
      float v = rp[i];
      if (v > thr) { int p = atomicAdd(&s_cnt, 1); if (p < MCAP) { cv[p] = v; ci[p] = (unsigned)i; } }
    }
    for (int i = tail_start + tid; i < V; i += TPB) {
      float v = rp[i];
      if (v > thr) { int p = atomicAdd(&s_cnt, 1); if (p < MCAP) { cv[p] = v; ci[p] = (unsigned)i; } }
    }
    for (int j = tid; j < nvec; j += TPB) {
      float4 v = vp[j];
      int base = head + 4 * j;
      if (v.x > thr) { int p = atomicAdd(&s_cnt, 1); if (p < MCAP) { cv[p] = v.x; ci[p] = (unsigned)(base + 0); } }
      if (v.y > thr) { int p = atomicAdd(&s_cnt, 1); if (p < MCAP) { cv[p] = v.y; ci[p] = (unsigned)(base + 1); } }
      if (v.z > thr) { int p = atomicAdd(&s_cnt, 1); if (p < MCAP) { cv[p] = v.z; ci[p] = (unsigned)(base + 2); } }
      if (v.w > thr) { int p = atomicAdd(&s_cnt, 1); if (p < MCAP) { cv[p] = v.w; ci[p] = (unsigned)(base + 3); } }
    }
    __syncthreads();
    cnt = s_cnt;
    if (cnt >= k && cnt <= MCAP) break;
    if (hi <= lo + 1u) break;
    if (cnt > MCAP) lo = tu; else hi = tu;
    unsigned mid = (unsigned)(((unsigned long long)lo + (unsigned long long)hi) >> 1);
    if (mid == tu) break;
    tu = mid;
    __syncthreads();
  }
  if (cnt > MCAP) cnt = MCAP;

  int np2 = 64;
  while (np2 < cnt) np2 <<= 1;
  for (int i = cnt + tid; i < np2; i += TPB) { cv[i] = -INFINITY; ci[i] = 0xFFFFFFFFu; }
  __syncthreads();

  bitonic_desc(cv, ci, np2, tid);

  float* out_vals = out;
  float* out_idx  = out + out_half;
  for (int t = tid; t < k; t += TPB) {
    out_vals[(size_t)row * k + t] = cv[t];
    out_idx[(size_t)row * k + t]  = (float)ci[t];
  }
}

extern "C" void kernel_launch(void* const* d_in, const int* in_sizes, int n_in,
                              void* d_out, int out_size, void* d_ws, size_t ws_size,
                              hipStream_t stream) {
  const float* x = (const float*)d_in[0];
  const int k = 50;
  const int out_half = out_size / 2;  // rows * k
  const int rows = out_half / k;      // 8192
  const int V = in_sizes[0] / rows;   // 50257

  // ws layout: [cnt: rows*4B][pad->256B][vals: rows*cap*4B][idx: rows*cap*4B]
  int cap = 0;
  size_t cnt_off = ((size_t)rows * 4 + 255) & ~(size_t)255;
  for (int c = SCAP; c >= 128; c >>= 1) {
    size_t need = cnt_off + (size_t)rows * (size_t)c * 8;
    if (need <= ws_size) { cap = c; break; }
  }

  dim3 grid(rows), block(TPB);
  if (cap >= 128) {
    char* ws = (char*)d_ws;
    int* wscnt = (int*)ws;
    float* wsv = (float*)(ws + cnt_off);
    unsigned* wsi = (unsigned*)(ws + cnt_off + (size_t)rows * (size_t)cap * 4);
    hipLaunchKernelGGL(topk_scan_kernel, grid, block, 0, stream,
                       x, wsv, wsi, wscnt, rows, V, k, cap);
    hipLaunchKernelGGL(topk_sort_kernel, grid, block, 0, stream,
                       wsv, wsi, wscnt, (float*)d_out, rows, k, cap, out_half);
  } else {
    hipLaunchKernelGGL(topk_mono_kernel, grid, block, 0, stream,
                       x, (float*)d_out, rows, V, k, out_half);
  }
}